// Round 2
// baseline (1139.879 us; speedup 1.0000x reference)
//
#include <hip/hip_runtime.h>

#define BATCH 2
#define NPTS  16384
#define BN    (BATCH * NPTS)
#define DIN   64
#define DM    128
#define NM    16

// ---------------------------------------------------------------------------
// Kernel 1: per-point projections.
//   f  = feature @ fc1_w + fc1_b
//   q  = f @ wq ; kf = f @ wk ; vf = f @ wv        (gather commutes with linear)
//   out = feature @ sc_w + sc_b                    (shortcut, written to d_out)
// 64 points per block, 256 threads. j = output channel, 2 groups x 32 points.
// ---------------------------------------------------------------------------
__global__ __launch_bounds__(256) void k_proj(
    const float* __restrict__ feat,
    const float* __restrict__ fc1_w, const float* __restrict__ fc1_b,
    const float* __restrict__ wq, const float* __restrict__ wk, const float* __restrict__ wv,
    const float* __restrict__ sc_w, const float* __restrict__ sc_b,
    float* __restrict__ qo, float* __restrict__ kfo, float* __restrict__ vfo,
    float* __restrict__ outp)
{
    __shared__ __align__(16) float featb[64][DIN];  // 16 KB
    __shared__ __align__(16) float fbuf[64][DM];    // 32 KB
    const int tid = threadIdx.x;
    const int p0  = blockIdx.x * 64;

    // stage feature tile (64 x 64 floats), coalesced
    #pragma unroll
    for (int k = 0; k < 4; ++k) {
        int i4 = tid + k * 256;
        ((float4*)featb)[i4] = ((const float4*)(feat + (size_t)p0 * DIN))[i4];
    }
    __syncthreads();

    const int j    = tid & 127;
    const int base = (tid >> 7) * 32;
    float acc[32];

    // f = feat @ fc1_w + fc1_b   -> fbuf
    #pragma unroll
    for (int pp = 0; pp < 32; ++pp) acc[pp] = fc1_b[j];
    for (int c = 0; c < DIN; c += 4) {
        float w0 = fc1_w[(c + 0) * DM + j];
        float w1 = fc1_w[(c + 1) * DM + j];
        float w2 = fc1_w[(c + 2) * DM + j];
        float w3 = fc1_w[(c + 3) * DM + j];
        #pragma unroll
        for (int pp = 0; pp < 32; ++pp) {
            float4 a = *(const float4*)&featb[base + pp][c];
            acc[pp] += a.x * w0 + a.y * w1 + a.z * w2 + a.w * w3;
        }
    }
    #pragma unroll
    for (int pp = 0; pp < 32; ++pp) fbuf[base + pp][j] = acc[pp];
    __syncthreads();

    // q / kf / vf  (no bias)
    for (int pass = 0; pass < 3; ++pass) {
        const float* W = pass == 0 ? wq : (pass == 1 ? wk : wv);
        float*       O = pass == 0 ? qo : (pass == 1 ? kfo : vfo);
        #pragma unroll
        for (int pp = 0; pp < 32; ++pp) acc[pp] = 0.f;
        for (int c = 0; c < DM; c += 4) {
            float w0 = W[(c + 0) * DM + j];
            float w1 = W[(c + 1) * DM + j];
            float w2 = W[(c + 2) * DM + j];
            float w3 = W[(c + 3) * DM + j];
            #pragma unroll
            for (int pp = 0; pp < 32; ++pp) {
                float4 a = *(const float4*)&fbuf[base + pp][c];
                acc[pp] += a.x * w0 + a.y * w1 + a.z * w2 + a.w * w3;
            }
        }
        #pragma unroll
        for (int pp = 0; pp < 32; ++pp) O[(size_t)(p0 + base + pp) * DM + j] = acc[pp];
    }

    // shortcut -> d_out
    #pragma unroll
    for (int pp = 0; pp < 32; ++pp) acc[pp] = sc_b[j];
    for (int c = 0; c < DIN; c += 4) {
        float w0 = sc_w[(c + 0) * DM + j];
        float w1 = sc_w[(c + 1) * DM + j];
        float w2 = sc_w[(c + 2) * DM + j];
        float w3 = sc_w[(c + 3) * DM + j];
        #pragma unroll
        for (int pp = 0; pp < 32; ++pp) {
            float4 a = *(const float4*)&featb[base + pp][c];
            acc[pp] += a.x * w0 + a.y * w1 + a.z * w2 + a.w * w3;
        }
    }
    #pragma unroll
    for (int pp = 0; pp < 32; ++pp) outp[(size_t)(p0 + base + pp) * DM + j] = acc[pp];
}

// ---------------------------------------------------------------------------
// Kernel 2: per-(point, neighbor) MLPs + vector-attention softmax.
// 1 wave = 1 point; lane owns channels {l, l+64}; all 16 neighbors processed
// simultaneously (32 independent accumulators per lane).
//
// abuf (matmul input, per wave, [row=channel 0..127][m 0..15]) is accessed as
// 4 float4 column-groups per row with an XOR swizzle: logical group g of row r
// lives at storage group g ^ ((r>>1)&3).
//   - writes (per-lane rows {lane, 64+lane}, stride 64 B): period-8 bank
//     pattern -> conflict-free b128 stores (was 32-way conflicted b32).
//   - reads in the matmul are wave-uniform broadcasts (conflict-free); the
//     permutation (cc>>1)&3 is compile-time under full unroll.
// ---------------------------------------------------------------------------
#define ASW(r) (((r) >> 1) & 3)

#define FMA16(O, W) do { \
    O[0]  += a0.x * (W); O[1]  += a0.y * (W); O[2]  += a0.z * (W); O[3]  += a0.w * (W); \
    O[4]  += a1.x * (W); O[5]  += a1.y * (W); O[6]  += a1.z * (W); O[7]  += a1.w * (W); \
    O[8]  += a2.x * (W); O[9]  += a2.y * (W); O[10] += a2.z * (W); O[11] += a2.w * (W); \
    O[12] += a3.x * (W); O[13] += a3.y * (W); O[14] += a3.z * (W); O[15] += a3.w * (W); } while (0)

__device__ __forceinline__ void mm128(
    const float* __restrict__ Wg,          // global 128x128 row-major weights
    float (* __restrict__ wbuf)[DM],       // block-shared chunk buffer [16][128]
    const float (* __restrict__ aw)[NM],   // this wave's abuf [128][16] (swizzled)
    float* __restrict__ o0, float* __restrict__ o1,
    int tid, int lane)
{
    for (int c0 = 0; c0 < DM; c0 += 16) {
        __syncthreads();                   // previous chunk fully consumed
        #pragma unroll
        for (int k2 = 0; k2 < 2; ++k2) {
            int i4 = tid + k2 * 256;       // 512 float4 = 16x128 floats
            ((float4*)wbuf)[i4] = ((const float4*)(Wg + (size_t)c0 * DM))[i4];
        }
        __syncthreads();                   // chunk ready
        #pragma unroll
        for (int cc = 0; cc < 16; ++cc) {
            const int s = (cc >> 1) & 3;   // == ASW(c0+cc), c0 % 16 == 0
            float w0 = wbuf[cc][lane];
            float w1 = wbuf[cc][64 + lane];
            const float4* ar = (const float4*)&aw[c0 + cc][0];
            const float4 a0 = ar[0 ^ s];
            const float4 a1 = ar[1 ^ s];
            const float4 a2 = ar[2 ^ s];
            const float4 a3 = ar[3 ^ s];
            FMA16(o0, w0);
            FMA16(o1, w1);
        }
    }
}

__global__ __launch_bounds__(256, 2) void k_attn(
    const float* __restrict__ xyz, const int* __restrict__ nidx,
    const float* __restrict__ qg, const float* __restrict__ kfg, const float* __restrict__ vfg,
    const float* __restrict__ dw1, const float* __restrict__ db1,
    const float* __restrict__ dw2, const float* __restrict__ db2,
    const float* __restrict__ gw1, const float* __restrict__ gb1,
    const float* __restrict__ gw2, const float* __restrict__ gb2,
    float* __restrict__ ao)
{
    __shared__ __align__(16) float abuf[4][DM][NM];  // 32 KB  matmul input (swizzled)
    __shared__ __align__(16) float obuf[4][NM][DM];  // 32 KB  qk staging, then v+pos
    __shared__ __align__(16) float wbuf[16][DM];     // 8 KB   weight chunk
    __shared__ __align__(16) float raws[4][NM][4];
    __shared__ int idxs[4][NM];

    const int tid  = threadIdx.x;
    const int wave = tid >> 6;
    const int lane = tid & 63;
    const int p    = blockIdx.x * 4 + wave;          // global point, 0..32767
    const int b    = p >> 14;                        // batch

    if (lane < NM) {
        int jj = nidx[(size_t)p * NM + lane];
        idxs[wave][lane] = jj;
        const float* xc = xyz + (size_t)p * 3;
        const float* xn = xyz + ((size_t)b * NPTS + jj) * 3;
        raws[wave][lane][0] = xc[0] - xn[0];
        raws[wave][lane][1] = xc[1] - xn[1];
        raws[wave][lane][2] = xc[2] - xn[2];
        raws[wave][lane][3] = 0.f;
    }
    const float q0 = qg[(size_t)p * DM + lane];
    const float q1 = qg[(size_t)p * DM + 64 + lane];
    __syncthreads();

    const int sw = ASW(lane);                        // same for rows lane and 64+lane
    float4* arow0 = (float4*)&abuf[wave][lane][0];
    float4* arow1 = (float4*)&abuf[wave][64 + lane][0];

    // qk = q - kf[idx]  -> obuf
    #pragma unroll 4
    for (int m = 0; m < NM; ++m) {
        int jj = idxs[wave][m];
        size_t r = ((size_t)b * NPTS + jj) * DM;
        obuf[wave][m][lane]      = q0 - kfg[r + lane];
        obuf[wave][m][64 + lane] = q1 - kfg[r + 64 + lane];
    }

    float o0[16], o1[16];

    // phase A: h1 = relu(raw @ dw1 + db1) -> abuf (swizzled float4 stores)
    {
        float wA0 = dw1[lane],          wB0 = dw1[64 + lane];
        float wA1 = dw1[DM + lane],     wB1 = dw1[DM + 64 + lane];
        float wA2 = dw1[2 * DM + lane], wB2 = dw1[2 * DM + 64 + lane];
        float bA = db1[lane], bB = db1[64 + lane];
        #pragma unroll
        for (int m = 0; m < NM; ++m) {
            float4 r4 = *(const float4*)&raws[wave][m][0];
            o0[m] = fmaxf(bA + r4.x * wA0 + r4.y * wA1 + r4.z * wA2, 0.f);
            o1[m] = fmaxf(bB + r4.x * wB0 + r4.y * wB1 + r4.z * wB2, 0.f);
        }
        #pragma unroll
        for (int g = 0; g < 4; ++g) {
            arow0[g ^ sw] = make_float4(o0[4*g+0], o0[4*g+1], o0[4*g+2], o0[4*g+3]);
            arow1[g ^ sw] = make_float4(o1[4*g+0], o1[4*g+1], o1[4*g+2], o1[4*g+3]);
        }
    }

    // layer B: pos = h1 @ dw2 + db2
    {
        float bA = db2[lane], bB = db2[64 + lane];
        #pragma unroll
        for (int m = 0; m < NM; ++m) { o0[m] = bA; o1[m] = bB; }
    }
    mm128(dw2, wbuf, abuf[wave], o0, o1, tid, lane);

    // a = qk + pos -> abuf (keep pos in o0/o1)
    #pragma unroll
    for (int g = 0; g < 4; ++g) {
        float4 t0, t1;
        t0.x = obuf[wave][4*g+0][lane] + o0[4*g+0];
        t0.y = obuf[wave][4*g+1][lane] + o0[4*g+1];
        t0.z = obuf[wave][4*g+2][lane] + o0[4*g+2];
        t0.w = obuf[wave][4*g+3][lane] + o0[4*g+3];
        t1.x = obuf[wave][4*g+0][64 + lane] + o1[4*g+0];
        t1.y = obuf[wave][4*g+1][64 + lane] + o1[4*g+1];
        t1.z = obuf[wave][4*g+2][64 + lane] + o1[4*g+2];
        t1.w = obuf[wave][4*g+3][64 + lane] + o1[4*g+3];
        arow0[g ^ sw] = t0;
        arow1[g ^ sw] = t1;
    }
    // vpos = vf[idx] + pos -> obuf (overwrite)
    #pragma unroll 4
    for (int m = 0; m < NM; ++m) {
        int jj = idxs[wave][m];
        size_t r = ((size_t)b * NPTS + jj) * DM;
        obuf[wave][m][lane]      = vfg[r + lane] + o0[m];
        obuf[wave][m][64 + lane] = vfg[r + 64 + lane] + o1[m];
    }

    // layer C: h2 = relu(a @ gw1 + gb1) -> abuf
    {
        float bA = gb1[lane], bB = gb1[64 + lane];
        #pragma unroll
        for (int m = 0; m < NM; ++m) { o0[m] = bA; o1[m] = bB; }
    }
    mm128(gw1, wbuf, abuf[wave], o0, o1, tid, lane);
    #pragma unroll
    for (int g = 0; g < 4; ++g) {
        arow0[g ^ sw] = make_float4(fmaxf(o0[4*g+0], 0.f), fmaxf(o0[4*g+1], 0.f),
                                    fmaxf(o0[4*g+2], 0.f), fmaxf(o0[4*g+3], 0.f));
        arow1[g ^ sw] = make_float4(fmaxf(o1[4*g+0], 0.f), fmaxf(o1[4*g+1], 0.f),
                                    fmaxf(o1[4*g+2], 0.f), fmaxf(o1[4*g+3], 0.f));
    }

    // layer D: s = (h2 @ gw2 + gb2) / sqrt(128)
    {
        float bA = gb2[lane], bB = gb2[64 + lane];
        #pragma unroll
        for (int m = 0; m < NM; ++m) { o0[m] = bA; o1[m] = bB; }
    }
    mm128(gw2, wbuf, abuf[wave], o0, o1, tid, lane);

    const float scale = 0.08838834764831845f;  // 1/sqrt(128)
    float mx0 = -1e30f, mx1 = -1e30f;
    #pragma unroll
    for (int m = 0; m < NM; ++m) {
        o0[m] *= scale; o1[m] *= scale;
        mx0 = fmaxf(mx0, o0[m]); mx1 = fmaxf(mx1, o1[m]);
    }
    float s0 = 0.f, s1 = 0.f, r0 = 0.f, r1 = 0.f;
    #pragma unroll
    for (int m = 0; m < NM; ++m) {
        float e0 = __expf(o0[m] - mx0);
        float e1 = __expf(o1[m] - mx1);
        s0 += e0; s1 += e1;
        r0 += e0 * obuf[wave][m][lane];
        r1 += e1 * obuf[wave][m][64 + lane];
    }
    ao[(size_t)p * DM + lane]      = r0 / s0;
    ao[(size_t)p * DM + 64 + lane] = r1 / s1;
}

// ---------------------------------------------------------------------------
// Kernel 3: out += attn_out @ fc2_w + fc2_b   (shortcut already in d_out)
// ---------------------------------------------------------------------------
__global__ __launch_bounds__(256) void k_final(
    const float* __restrict__ aog,
    const float* __restrict__ fc2_w, const float* __restrict__ fc2_b,
    float* __restrict__ outp)
{
    __shared__ __align__(16) float ab[64][DM];  // 32 KB
    const int tid = threadIdx.x;
    const int p0  = blockIdx.x * 64;

    #pragma unroll
    for (int k = 0; k < 8; ++k) {
        int i4 = tid + k * 256;
        ((float4*)ab)[i4] = ((const float4*)(aog + (size_t)p0 * DM))[i4];
    }
    __syncthreads();

    const int j    = tid & 127;
    const int base = (tid >> 7) * 32;
    float acc[32];
    #pragma unroll
    for (int pp = 0; pp < 32; ++pp) acc[pp] = fc2_b[j];
    for (int c = 0; c < DM; c += 4) {
        float w0 = fc2_w[(c + 0) * DM + j];
        float w1 = fc2_w[(c + 1) * DM + j];
        float w2 = fc2_w[(c + 2) * DM + j];
        float w3 = fc2_w[(c + 3) * DM + j];
        #pragma unroll
        for (int pp = 0; pp < 32; ++pp) {
            float4 a = *(const float4*)&ab[base + pp][c];
            acc[pp] += a.x * w0 + a.y * w1 + a.z * w2 + a.w * w3;
        }
    }
    #pragma unroll
    for (int pp = 0; pp < 32; ++pp) {
        size_t o = (size_t)(p0 + base + pp) * DM + j;
        outp[o] += acc[pp];
    }
}

// ---------------------------------------------------------------------------
extern "C" void kernel_launch(void* const* d_in, const int* in_sizes, int n_in,
                              void* d_out, int out_size, void* d_ws, size_t ws_size,
                              hipStream_t stream)
{
    const float* xyz     = (const float*)d_in[0];
    const float* feature = (const float*)d_in[1];
    const int*   nidx    = (const int*)d_in[2];
    const float* dw1     = (const float*)d_in[3];
    const float* db1     = (const float*)d_in[4];
    const float* dw2     = (const float*)d_in[5];
    const float* db2     = (const float*)d_in[6];
    const float* fc1_w   = (const float*)d_in[7];
    const float* fc1_b   = (const float*)d_in[8];
    const float* wq      = (const float*)d_in[9];
    const float* wk      = (const float*)d_in[10];
    const float* wv      = (const float*)d_in[11];
    const float* gw1     = (const float*)d_in[12];
    const float* gb1     = (const float*)d_in[13];
    const float* gw2     = (const float*)d_in[14];
    const float* gb2     = (const float*)d_in[15];
    const float* fc2_w   = (const float*)d_in[16];
    const float* fc2_b   = (const float*)d_in[17];
    const float* sc_w    = (const float*)d_in[18];
    const float* sc_b    = (const float*)d_in[19];

    float* ws = (float*)d_ws;
    const size_t SZ = (size_t)BN * DM;   // 4,194,304 floats
    float* q  = ws;
    float* kf = ws + SZ;
    float* vf = ws + 2 * SZ;
    float* ao = q;                       // attn-out aliases q (each wave only
                                         // reads its own q row before writing it)
    float* out = (float*)d_out;

    k_proj<<<BN / 64, 256, 0, stream>>>(feature, fc1_w, fc1_b, wq, wk, wv,
                                        sc_w, sc_b, q, kf, vf, out);
    k_attn<<<BN / 4, 256, 0, stream>>>(xyz, nidx, q, kf, vf,
                                       dw1, db1, dw2, db2,
                                       gw1, gb1, gw2, gb2, ao);
    k_final<<<BN / 64, 256, 0, stream>>>(ao, fc2_w, fc2_b, out);
}